// Round 4
// baseline (3990.526 us; speedup 1.0000x reference)
//
#include <hip/hip_runtime.h>

#define Bn 256
#define Tn 512
#define Fn 128
#define Un 512
#define XFn 129      // F + 1 (interval)
#define BM 16        // batch rows per group
#define GC 16        // WGs per group (512 cols / 32)
#define NG 16        // groups (256 rows / 16)
#define XS 136       // x row stride in shorts (272 B, 16B-aligned)
#define HS 520       // h row stride in shorts (1040 B, 16B-aligned)
#define KT 20        // K tiles: 640 / 32

typedef __attribute__((ext_vector_type(8))) short short8;
typedef __attribute__((ext_vector_type(4))) float floatx4;
typedef unsigned long long ull;

__device__ __forceinline__ unsigned short f2bf(float f) {
  unsigned u = __float_as_uint(f);
  u += 0x7fffu + ((u >> 16) & 1u);            // RNE
  return (unsigned short)(u >> 16);
}
__device__ __forceinline__ float bf2f(unsigned v) {       // low 16 bits
  return __uint_as_float((v & 0xffffu) << 16);
}
__device__ __forceinline__ ull pack4(float a, float b, float c, float d) {
  return (ull)f2bf(a) | ((ull)f2bf(b) << 16) | ((ull)f2bf(c) << 32) | ((ull)f2bf(d) << 48);
}

// ---- communication primitives --------------------------------------------
// ALL comm traffic (data + flags) uses agent-scope relaxed atomics — the
// per-instruction sc0 sc1 (MALL-coherent) codegen proven correct by the
// 3150us baseline. No cache-wide maintenance is emitted. A flag is stored
// only after s_waitcnt vmcnt(0) drains the data stores, so flag-visible
// implies data-visible at the MALL for any consumer using these loads.
__device__ __forceinline__ ull ldc8(const void* p) {
  return __hip_atomic_load((const ull*)p, __ATOMIC_RELAXED, __HIP_MEMORY_SCOPE_AGENT);
}
__device__ __forceinline__ void stc8(void* p, ull v) {
  __hip_atomic_store((ull*)p, v, __ATOMIC_RELAXED, __HIP_MEMORY_SCOPE_AGENT);
}

// Spin until all 32 per-producer-wave flags reach tgt (one coalesced load
// per wave per poll; flags are plain monotone stores, no RMW convoy).
__device__ __forceinline__ void poll32(const unsigned* flags, unsigned tgt) {
  const unsigned* p = flags + (threadIdx.x & 31);
  for (;;) {
    unsigned f = __hip_atomic_load(p, __ATOMIC_RELAXED, __HIP_MEMORY_SCOPE_AGENT);
    if (__all((int)(f >= tgt))) return;
    __builtin_amdgcn_s_sleep(1);
  }
}

// Gather 64B (cols c0,c0+1 of buf_T[col][16 rows bf16]) and write the
// transposed 16-row x 2-col block into dst (row-major [16][HS]).
__device__ __forceinline__ void gather_T(short* dst, const unsigned short* src) {
  const int c0 = (int)threadIdx.x * 2;
  const ull* q = (const ull*)(src + (size_t)c0 * BM);
  ull v[8];
  #pragma unroll
  for (int i = 0; i < 8; ++i) v[i] = ldc8(q + i);
  #pragma unroll
  for (int r = 0; r < 16; ++r) {
    unsigned lo = (unsigned)((v[r >> 2]       >> ((r & 3) * 16)) & 0xffffu);
    unsigned hi = (unsigned)((v[4 + (r >> 2)] >> ((r & 3) * 16)) & 0xffffu);
    *(unsigned*)&dst[r * HS + c0] = lo | (hi << 16);
  }
}

// ws u32[0..1023]: flags, 16 groups x 64 (h flags [0..31], hr flags [32..63])
__global__ void init_ws(unsigned* w) {
  int i = blockIdx.x * 256 + threadIdx.x;
  if (i < 1024) w[i] = 0u;
}

__global__ __launch_bounds__(256, 1)
void gru_kernel(const float* __restrict__ inp, const float* __restrict__ h0,
                const float* __restrict__ wz, const float* __restrict__ uz, const float* __restrict__ bz_,
                const float* __restrict__ wr, const float* __restrict__ ur, const float* __restrict__ br_,
                const float* __restrict__ wh, const float* __restrict__ uh, const float* __restrict__ bh_,
                const float* __restrict__ wint_, const float* __restrict__ bint_,
                float* __restrict__ out,
                unsigned short* __restrict__ h_buf, unsigned short* __restrict__ hr_buf,
                unsigned* __restrict__ flags)
{
  __shared__ short Xlds[2][16 * XS];   // x(t) bf16, double-buffered
  __shared__ short Ah[16 * HS];        // h(t-1)
  __shared__ short Bh[16 * HS];        // h(t-1).*r  (separate buffer -> no S2)
  __shared__ float ivals[2][16];

  const int tid  = threadIdx.x;
  const int wave = tid >> 6;
  const int lane = tid & 63;
  const int ln   = lane & 15;
  const int quad = lane >> 4;
  const int g    = blockIdx.x & 15;
  const int wg   = blockIdx.x >> 4;   // N-slice 0..15

  unsigned* gflags = flags + g * 64;
  unsigned short* hrg = hr_buf + (size_t)g * (Un * BM);  // [512 cols][16 rows]
  unsigned short* hg  = h_buf  + (size_t)g * (Un * BM);

  // ---- persistent register-resident weights ----
  const float* gw1 = (wave < 2) ? wz : wr;
  const float* gu1 = (wave < 2) ? uz : ur;
  const int ncol1 = wg * 32 + (wave & 1) * 16 + ln;     // gate-1 col (z for w0/1, r for w2/3)
  short8 bf1[KT];
  #pragma unroll
  for (int kk = 0; kk < KT; ++kk) {
    short8 v;
    #pragma unroll
    for (int j = 0; j < 8; ++j) {
      int k = kk * 32 + quad * 8 + j;
      float w = (k < Fn) ? gw1[k * Un + ncol1] : gu1[(k - Fn) * Un + ncol1];
      v[j] = (short)f2bf(w);
    }
    bf1[kk] = v;
  }
  const int ncol2 = wg * 32 + wave * 16 + ln;           // valid for wave<2 (== ncol1 there)
  short8 bf2[KT];
  if (wave < 2) {
    #pragma unroll
    for (int kk = 0; kk < KT; ++kk) {
      short8 v;
      #pragma unroll
      for (int j = 0; j < 8; ++j) {
        int k = kk * 32 + quad * 8 + j;
        float w = (k < Fn) ? wh[k * Un + ncol2] : uh[(k - Fn) * Un + ncol2];
        v[j] = (short)f2bf(w);
      }
      bf2[kk] = v;
    }
  }

  const float bz = bz_[0], br = br_[0], bh = bh_[0], bint = bint_[0];
  const float wint = (wave < 2) ? wint_[ncol2] : 0.f;

  float hold[4] = {0.f, 0.f, 0.f, 0.f};
  if (wave < 2) {
    #pragma unroll
    for (int i = 0; i < 4; ++i)
      hold[i] = h0[(size_t)(g * BM + quad * 4 + i) * Un + ncol2];
  }

  // ---- prologue: stage x(0), ivals[0], Ah <- h0 ----
  {
    int row = tid >> 4, ch = tid & 15;
    const float* xr = inp + ((size_t)(g * BM + row) * Tn + 0) * XFn + ch * 8;
    short8 v;
    #pragma unroll
    for (int j = 0; j < 8; ++j) v[j] = (short)f2bf(xr[j]);
    *(short8*)&Xlds[0][row * XS + ch * 8] = v;
    if (tid < 16)
      ivals[0][tid] = inp[((size_t)(g * BM + tid) * Tn + 0) * XFn + Fn];
    const float* hp = h0 + (size_t)(g * BM + row) * Un + ch * 32;
    #pragma unroll
    for (int s = 0; s < 4; ++s) {
      short8 hv;
      #pragma unroll
      for (int j = 0; j < 8; ++j) hv[j] = (short)f2bf(hp[s * 8 + j]);
      *(short8*)&Ah[row * HS + ch * 32 + s * 8] = hv;
    }
  }

  // Flag protocol (monotone; single-buffered comm is race-free):
  //   hr(t) published with hrflag=t+1; h(t) published with hflag=t+1.
  //   Overwrite-safety: a WG writes hrg at step t only after S1, which
  //   follows poll(hflags>=t); peer hflag=t was stored after that peer's S3
  //   of t-1, i.e. after it finished gathering hr(t-1). A WG writes hg at
  //   step t only after S3, which follows poll(hrflags>=t+1); peer
  //   hrflag=t+1 was stored after that peer's S1 of t, i.e. after it
  //   finished gathering h(t-1). Visibility: flags stored after vmcnt(0)
  //   on the agent-scope data stores.
  for (int t = 0; t < Tn; ++t) {
    const int buf = t & 1;

    if (t > 0) {
      poll32(gflags, (unsigned)t);             // h(t-1) ready group-wide
      gather_T(Ah, hg);                        // stage + transpose h(t-1)
    }
    __syncthreads();                           // S1: Ah/Xlds visible

    // ---- phase 1: [x|h] @ [Wz;Uz | Wr;Ur], 4-way acc chain split ----
    floatx4 a0 = {0.f,0.f,0.f,0.f}, a1 = {0.f,0.f,0.f,0.f};
    floatx4 a2 = {0.f,0.f,0.f,0.f}, a3 = {0.f,0.f,0.f,0.f};
    {
      const short* xb = &Xlds[buf][ln * XS + quad * 8];
      const short* hb = &Ah[ln * HS + quad * 8];
      #pragma unroll
      for (int kk = 0; kk < KT; ++kk) {
        const short* ap = (kk < 4) ? (xb + kk * 32) : (hb + (kk - 4) * 32);
        short8 a = *(const short8*)ap;
        switch (kk & 3) {
          case 0: a0 = __builtin_amdgcn_mfma_f32_16x16x32_bf16(a, bf1[kk], a0, 0, 0, 0); break;
          case 1: a1 = __builtin_amdgcn_mfma_f32_16x16x32_bf16(a, bf1[kk], a1, 0, 0, 0); break;
          case 2: a2 = __builtin_amdgcn_mfma_f32_16x16x32_bf16(a, bf1[kk], a2, 0, 0, 0); break;
          default:a3 = __builtin_amdgcn_mfma_f32_16x16x32_bf16(a, bf1[kk], a3, 0, 0, 0); break;
        }
      }
    }
    float zf[4];
    {
      floatx4 acc = (a0 + a1) + (a2 + a3);
      if (wave < 2) {
        #pragma unroll
        for (int i = 0; i < 4; ++i) zf[i] = 1.f / (1.f + __expf(-(acc[i] + bz)));
      } else {
        // r producer also owns h(t-1) in Ah -> publish h.*r directly.
        // Round r to bf16 first: bit-identical to the baseline r-exchange.
        float hrv[4];
        #pragma unroll
        for (int i = 0; i < 4; ++i) {
          float rv = 1.f / (1.f + __expf(-(acc[i] + br)));
          float rb = bf2f((unsigned)f2bf(rv));
          unsigned hv = (unsigned short)Ah[(quad * 4 + i) * HS + ncol1];
          hrv[i] = bf2f(hv) * rb;
        }
        stc8(hrg + (size_t)ncol1 * BM + quad * 4,
             pack4(hrv[0], hrv[1], hrv[2], hrv[3]));
        asm volatile("s_waitcnt vmcnt(0)" ::: "memory");   // data at MALL
        if (lane == 0)
          __hip_atomic_store(&gflags[32 + wg * 2 + (wave & 1)], (unsigned)(t + 1),
                             __ATOMIC_RELAXED, __HIP_MEMORY_SCOPE_AGENT);
      }
    }
    // No S2 needed: hr-gather writes Bh only; any lagging phase-1 wave reads
    // Ah/Xlds only, and poll32 passes only after own waves 2/3 posted hrflag
    // (stored after their last Ah read in phase 1).
    poll32(gflags + 32, (unsigned)(t + 1));    // hr ready group-wide
    gather_T(Bh, hrg);                         // Bh := h(t-1).*r
    __syncthreads();                           // S3

    // ---- phase 2 (waves 0,1) + x(t+1) staging (waves 2,3) ----
    if (wave < 2) {
      floatx4 b0 = {0.f,0.f,0.f,0.f}, b1 = {0.f,0.f,0.f,0.f};
      floatx4 b2 = {0.f,0.f,0.f,0.f}, b3 = {0.f,0.f,0.f,0.f};
      const short* xb = &Xlds[buf][ln * XS + quad * 8];
      const short* hb = &Bh[ln * HS + quad * 8];
      #pragma unroll
      for (int kk = 0; kk < KT; ++kk) {
        const short* ap = (kk < 4) ? (xb + kk * 32) : (hb + (kk - 4) * 32);
        short8 a = *(const short8*)ap;
        switch (kk & 3) {
          case 0: b0 = __builtin_amdgcn_mfma_f32_16x16x32_bf16(a, bf2[kk], b0, 0, 0, 0); break;
          case 1: b1 = __builtin_amdgcn_mfma_f32_16x16x32_bf16(a, bf2[kk], b1, 0, 0, 0); break;
          case 2: b2 = __builtin_amdgcn_mfma_f32_16x16x32_bf16(a, bf2[kk], b2, 0, 0, 0); break;
          default:b3 = __builtin_amdgcn_mfma_f32_16x16x32_bf16(a, bf2[kk], b3, 0, 0, 0); break;
        }
      }
      floatx4 acc2 = (b0 + b1) + (b2 + b3);
      float hn[4];
      #pragma unroll
      for (int i = 0; i < 4; ++i) {
        int m = quad * 4 + i;
        float hh  = 1.f - 2.f / (__expf(2.f * (acc2[i] + bh)) + 1.f);
        float dec = __expf(-fmaxf(ivals[buf][m] * wint + bint, 0.f));
        float v   = dec * (zf[i] * hold[i] + (1.f - zf[i]) * hh);
        hold[i] = v; hn[i] = v;
      }
      stc8(hg + (size_t)ncol2 * BM + quad * 4,
           pack4(hn[0], hn[1], hn[2], hn[3]));
      asm volatile("s_waitcnt vmcnt(0)" ::: "memory");
      if (lane == 0)
        __hip_atomic_store(&gflags[wg * 2 + wave], (unsigned)(t + 1),
                           __ATOMIC_RELAXED, __HIP_MEMORY_SCOPE_AGENT);
      #pragma unroll
      for (int i = 0; i < 4; ++i) {            // out stores after flag: off critical path
        int m = quad * 4 + i;
        out[((size_t)(g * BM + m) * Tn + t) * Un + ncol2] = hn[i];
      }
    } else if (t + 1 < Tn) {
      int id = tid - 128;               // 0..127
      int row = id >> 3, ch = id & 7;   // 16 shorts per thread
      const float* xr = inp + ((size_t)(g * BM + row) * Tn + (t + 1)) * XFn + ch * 16;
      short8 v0, v1;
      #pragma unroll
      for (int j = 0; j < 8; ++j) { v0[j] = (short)f2bf(xr[j]); v1[j] = (short)f2bf(xr[8 + j]); }
      *(short8*)&Xlds[buf ^ 1][row * XS + ch * 16]     = v0;
      *(short8*)&Xlds[buf ^ 1][row * XS + ch * 16 + 8] = v1;
      if (id < 16)
        ivals[buf ^ 1][id] = inp[((size_t)(g * BM + id) * Tn + (t + 1)) * XFn + Fn];
    }

    __syncthreads();                           // S4: Ah/Bh/Xlds reuse next step
  }
}

extern "C" void kernel_launch(void* const* d_in, const int* in_sizes, int n_in,
                              void* d_out, int out_size, void* d_ws, size_t ws_size,
                              hipStream_t stream) {
  const float* inp  = (const float*)d_in[0];
  const float* h0   = (const float*)d_in[1];
  const float* wz   = (const float*)d_in[2];
  const float* uz   = (const float*)d_in[3];
  const float* bz   = (const float*)d_in[4];
  const float* wr   = (const float*)d_in[5];
  const float* ur   = (const float*)d_in[6];
  const float* br   = (const float*)d_in[7];
  const float* wh   = (const float*)d_in[8];
  const float* uh   = (const float*)d_in[9];
  const float* bh   = (const float*)d_in[10];
  const float* wint = (const float*)d_in[11];
  const float* bint = (const float*)d_in[12];
  float* out = (float*)d_out;

  // ws: [0,4KB) flags | [8KB,264KB) h_buf_T | [264KB,520KB) hr_buf_T
  unsigned* flags       = (unsigned*)d_ws;
  unsigned short* h_buf = (unsigned short*)((char*)d_ws + 8192);
  unsigned short* hr_buf= (unsigned short*)((char*)d_ws + 8192 + (size_t)Bn * Un * 2);

  hipLaunchKernelGGL(init_ws, dim3(4), dim3(256), 0, stream, flags);

  void* args[] = {(void*)&inp, (void*)&h0, (void*)&wz, (void*)&uz, (void*)&bz,
                  (void*)&wr, (void*)&ur, (void*)&br, (void*)&wh, (void*)&uh,
                  (void*)&bh, (void*)&wint, (void*)&bint, (void*)&out,
                  (void*)&h_buf, (void*)&hr_buf, (void*)&flags};
  hipError_t e = hipLaunchCooperativeKernel((void*)gru_kernel, dim3(NG * GC), dim3(256),
                                            args, 0, stream);
  if (e != hipSuccess) {
    hipLaunchKernelGGL(gru_kernel, dim3(NG * GC), dim3(256), 0, stream,
                       inp, h0, wz, uz, bz, wr, ur, br, wh, uh, bh, wint, bint,
                       out, h_buf, hr_buf, flags);
  }
}

// Round 5
// 3347.580 us; speedup vs baseline: 1.1921x; 1.1921x over previous
//
#include <hip/hip_runtime.h>

#define Bn 256
#define Tn 512
#define Fn 128
#define Un 512
#define XFn 129      // F + 1 (interval)
#define BM 16        // batch rows per group
#define GC 16        // WGs per group (512 cols / 32)
#define NG 16        // groups (256 rows / 16)
#define XS 136       // x row stride in shorts (272 B, 16B-aligned)
#define HS 520       // h row stride in shorts (1040 B, 16B-aligned)
#define KT 20        // K tiles: 640 / 32

typedef __attribute__((ext_vector_type(8))) short short8;
typedef __attribute__((ext_vector_type(4))) float floatx4;
typedef unsigned long long ull;

__device__ __forceinline__ unsigned short f2bf(float f) {
  unsigned u = __float_as_uint(f);
  u += 0x7fffu + ((u >> 16) & 1u);            // RNE
  return (unsigned short)(u >> 16);
}
__device__ __forceinline__ float bf2f(unsigned v) {       // low 16 bits
  return __uint_as_float((v & 0xffffu) << 16);
}
__device__ __forceinline__ ull pack4(float a, float b, float c, float d) {
  return (ull)f2bf(a) | ((ull)f2bf(b) << 16) | ((ull)f2bf(c) << 32) | ((ull)f2bf(d) << 48);
}

// ---- communication primitives --------------------------------------------
// ALL comm traffic (data + flags) uses agent-scope relaxed atomics (per-
// instruction sc0 sc1 <-> MALL) — the codegen proven correct in rounds 0/4.
// A flag is stored only after s_waitcnt vmcnt(0) drains the data stores, so
// flag-visible implies data-visible at the MALL.
__device__ __forceinline__ ull ldc8(const void* p) {
  return __hip_atomic_load((const ull*)p, __ATOMIC_RELAXED, __HIP_MEMORY_SCOPE_AGENT);
}
__device__ __forceinline__ void stc8(void* p, ull v) {
  __hip_atomic_store((ull*)p, v, __ATOMIC_RELAXED, __HIP_MEMORY_SCOPE_AGENT);
}

// Single-wave poll: the calling WAVE spins until all 32 per-producer-wave
// flags reach tgt. Only one wave per WG calls this (contention fix: 64
// pollers/group on one 128B line instead of 4096 in round 4); the following
// __syncthreads releases the other waves.
__device__ __forceinline__ void pollw(const unsigned* flags, unsigned tgt) {
  const unsigned* p = flags + (threadIdx.x & 31);
  for (;;) {
    unsigned f = __hip_atomic_load(p, __ATOMIC_RELAXED, __HIP_MEMORY_SCOPE_AGENT);
    if (__all((int)(f >= tgt))) return;
    __builtin_amdgcn_s_sleep(1);
  }
}

// Gather 64B (cols c0,c0+1 of buf_T[col][16 rows bf16]) and write the
// transposed 16-row x 2-col block into dst (row-major [16][HS]).
__device__ __forceinline__ void gather_T(short* dst, const unsigned short* src) {
  const int c0 = (int)threadIdx.x * 2;
  const ull* q = (const ull*)(src + (size_t)c0 * BM);
  ull v[8];
  #pragma unroll
  for (int i = 0; i < 8; ++i) v[i] = ldc8(q + i);
  #pragma unroll
  for (int r = 0; r < 16; ++r) {
    unsigned lo = (unsigned)((v[r >> 2]       >> ((r & 3) * 16)) & 0xffffu);
    unsigned hi = (unsigned)((v[4 + (r >> 2)] >> ((r & 3) * 16)) & 0xffffu);
    *(unsigned*)&dst[r * HS + c0] = lo | (hi << 16);
  }
}

// ws u32[0..1023]: flags, 16 groups x 64 (h flags [0..31], hr flags [32..63])
__global__ void init_ws(unsigned* w) {
  int i = blockIdx.x * 256 + threadIdx.x;
  if (i < 1024) w[i] = 0u;
}

__global__ __launch_bounds__(256, 1)
void gru_kernel(const float* __restrict__ inp, const float* __restrict__ h0,
                const float* __restrict__ wz, const float* __restrict__ uz, const float* __restrict__ bz_,
                const float* __restrict__ wr, const float* __restrict__ ur, const float* __restrict__ br_,
                const float* __restrict__ wh, const float* __restrict__ uh, const float* __restrict__ bh_,
                const float* __restrict__ wint_, const float* __restrict__ bint_,
                float* __restrict__ out,
                unsigned short* __restrict__ h_buf, unsigned short* __restrict__ hr_buf,
                unsigned* __restrict__ flags)
{
  __shared__ short Xlds[2][16 * XS];   // x(t) bf16, double-buffered
  __shared__ short Ah[16 * HS];        // h(t-1)
  __shared__ short Bh[16 * HS];        // h(t-1).*r  (separate buffer -> no S2)
  __shared__ float ivals[2][16];

  const int tid  = threadIdx.x;
  const int wave = tid >> 6;
  const int lane = tid & 63;
  const int ln   = lane & 15;
  const int quad = lane >> 4;
  const int g    = blockIdx.x & 15;
  const int wg   = blockIdx.x >> 4;   // N-slice 0..15

  unsigned* gflags = flags + g * 64;
  unsigned short* hrg = hr_buf + (size_t)g * (Un * BM);  // [512 cols][16 rows]
  unsigned short* hg  = h_buf  + (size_t)g * (Un * BM);

  // ---- persistent register-resident weights ----
  const float* gw1 = (wave < 2) ? wz : wr;
  const float* gu1 = (wave < 2) ? uz : ur;
  const int ncol1 = wg * 32 + (wave & 1) * 16 + ln;     // gate-1 col (z for w0/1, r for w2/3)
  short8 bf1[KT];
  #pragma unroll
  for (int kk = 0; kk < KT; ++kk) {
    short8 v;
    #pragma unroll
    for (int j = 0; j < 8; ++j) {
      int k = kk * 32 + quad * 8 + j;
      float w = (k < Fn) ? gw1[k * Un + ncol1] : gu1[(k - Fn) * Un + ncol1];
      v[j] = (short)f2bf(w);
    }
    bf1[kk] = v;
  }
  const int ncol2 = wg * 32 + wave * 16 + ln;           // valid for wave<2 (== ncol1 there)
  short8 bf2[KT];
  if (wave < 2) {
    #pragma unroll
    for (int kk = 0; kk < KT; ++kk) {
      short8 v;
      #pragma unroll
      for (int j = 0; j < 8; ++j) {
        int k = kk * 32 + quad * 8 + j;
        float w = (k < Fn) ? wh[k * Un + ncol2] : uh[(k - Fn) * Un + ncol2];
        v[j] = (short)f2bf(w);
      }
      bf2[kk] = v;
    }
  }

  const float bz = bz_[0], br = br_[0], bh = bh_[0], bint = bint_[0];
  const float wint = (wave < 2) ? wint_[ncol2] : 0.f;

  float hold[4] = {0.f, 0.f, 0.f, 0.f};
  if (wave < 2) {
    #pragma unroll
    for (int i = 0; i < 4; ++i)
      hold[i] = h0[(size_t)(g * BM + quad * 4 + i) * Un + ncol2];
  }

  // ---- prologue: stage x(0), ivals[0], Ah <- h0 ----
  {
    int row = tid >> 4, ch = tid & 15;
    const float* xr = inp + ((size_t)(g * BM + row) * Tn + 0) * XFn + ch * 8;
    short8 v;
    #pragma unroll
    for (int j = 0; j < 8; ++j) v[j] = (short)f2bf(xr[j]);
    *(short8*)&Xlds[0][row * XS + ch * 8] = v;
    if (tid < 16)
      ivals[0][tid] = inp[((size_t)(g * BM + tid) * Tn + 0) * XFn + Fn];
    const float* hp = h0 + (size_t)(g * BM + row) * Un + ch * 32;
    #pragma unroll
    for (int s = 0; s < 4; ++s) {
      short8 hv;
      #pragma unroll
      for (int j = 0; j < 8; ++j) hv[j] = (short)f2bf(hp[s * 8 + j]);
      *(short8*)&Ah[row * HS + ch * 32 + s * 8] = hv;
    }
  }
  __syncthreads();   // prologue stores visible (x-part at t=0 reads Xlds[0])

  // Flag protocol (monotone; single-buffered comm is race-free):
  //   hr(t) published with hrflag=t+1 (waves 2/3, after S1 of t);
  //   h(t)  published with hflag=t+1  (waves 0/1, after S3 of t).
  //   Overwrite-safety: hrg written at t only after poll(hflags>=t), and a
  //   peer's hflag=t was stored after its S3 of t-1, i.e. after it finished
  //   gathering hr(t-1). hg written at t only after poll(hrflags>=t+1), and
  //   a peer's hrflag=t+1 was stored after its S1 of t, i.e. after it
  //   finished gathering h(t-1). Visibility: flags stored after vmcnt(0).
  for (int t = 0; t < Tn; ++t) {
    const int buf = t & 1;

    // ---- phase-1 x-part (no h dependency): runs before/during h-exchange
    floatx4 a0 = {0.f,0.f,0.f,0.f}, a1 = {0.f,0.f,0.f,0.f};
    floatx4 a2 = {0.f,0.f,0.f,0.f}, a3 = {0.f,0.f,0.f,0.f};
    {
      const short* xb = &Xlds[buf][ln * XS + quad * 8];
      a0 = __builtin_amdgcn_mfma_f32_16x16x32_bf16(*(const short8*)(xb),      bf1[0], a0, 0, 0, 0);
      a1 = __builtin_amdgcn_mfma_f32_16x16x32_bf16(*(const short8*)(xb + 32), bf1[1], a1, 0, 0, 0);
      a2 = __builtin_amdgcn_mfma_f32_16x16x32_bf16(*(const short8*)(xb + 64), bf1[2], a2, 0, 0, 0);
      a3 = __builtin_amdgcn_mfma_f32_16x16x32_bf16(*(const short8*)(xb + 96), bf1[3], a3, 0, 0, 0);
    }

    // ---- h exchange: wave-3 poll, barrier-release, all-thread gather ----
    if (t > 0) {
      if (wave == 3) pollw(gflags, (unsigned)t);   // h(t-1) ready group-wide
      __syncthreads();                             // Sp1: release
      gather_T(Ah, hg);                            // stage + transpose h(t-1)
    }
    __syncthreads();                               // S1: Ah visible

    // ---- phase-1 h-part: 16 MFMAs over Ah ----
    {
      const short* hb = &Ah[ln * HS + quad * 8];
      #pragma unroll
      for (int kk = 4; kk < KT; ++kk) {
        short8 a = *(const short8*)(hb + (kk - 4) * 32);
        switch (kk & 3) {
          case 0: a0 = __builtin_amdgcn_mfma_f32_16x16x32_bf16(a, bf1[kk], a0, 0, 0, 0); break;
          case 1: a1 = __builtin_amdgcn_mfma_f32_16x16x32_bf16(a, bf1[kk], a1, 0, 0, 0); break;
          case 2: a2 = __builtin_amdgcn_mfma_f32_16x16x32_bf16(a, bf1[kk], a2, 0, 0, 0); break;
          default:a3 = __builtin_amdgcn_mfma_f32_16x16x32_bf16(a, bf1[kk], a3, 0, 0, 0); break;
        }
      }
    }

    float zf[4];
    floatx4 b0 = {0.f,0.f,0.f,0.f}, b1 = {0.f,0.f,0.f,0.f};
    floatx4 b2 = {0.f,0.f,0.f,0.f}, b3 = {0.f,0.f,0.f,0.f};
    {
      floatx4 acc = (a0 + a1) + (a2 + a3);
      if (wave < 2) {
        #pragma unroll
        for (int i = 0; i < 4; ++i) zf[i] = 1.f / (1.f + __expf(-(acc[i] + bz)));
        // phase-2 x-part hoist: overlaps waves 2/3's publish + flag RT
        const short* xb = &Xlds[buf][ln * XS + quad * 8];
        b0 = __builtin_amdgcn_mfma_f32_16x16x32_bf16(*(const short8*)(xb),      bf2[0], b0, 0, 0, 0);
        b1 = __builtin_amdgcn_mfma_f32_16x16x32_bf16(*(const short8*)(xb + 32), bf2[1], b1, 0, 0, 0);
        b2 = __builtin_amdgcn_mfma_f32_16x16x32_bf16(*(const short8*)(xb + 64), bf2[2], b2, 0, 0, 0);
        b3 = __builtin_amdgcn_mfma_f32_16x16x32_bf16(*(const short8*)(xb + 96), bf2[3], b3, 0, 0, 0);
      } else {
        // r producer also owns h(t-1) in Ah -> publish h.*r directly.
        // Round r to bf16 first: bit-identical to the baseline r-exchange.
        float hrv[4];
        #pragma unroll
        for (int i = 0; i < 4; ++i) {
          float rv = 1.f / (1.f + __expf(-(acc[i] + br)));
          float rb = bf2f((unsigned)f2bf(rv));
          unsigned hv = (unsigned short)Ah[(quad * 4 + i) * HS + ncol1];
          hrv[i] = bf2f(hv) * rb;
        }
        stc8(hrg + (size_t)ncol1 * BM + quad * 4,
             pack4(hrv[0], hrv[1], hrv[2], hrv[3]));
        asm volatile("s_waitcnt vmcnt(0)" ::: "memory");   // data at MALL
        if (lane == 0)
          __hip_atomic_store(&gflags[32 + wg * 2 + (wave & 1)], (unsigned)(t + 1),
                             __ATOMIC_RELAXED, __HIP_MEMORY_SCOPE_AGENT);
      }
    }

    // ---- hr exchange (no S2 needed: gather writes Bh; stragglers read
    //      Ah/Xlds only, and wave 3 polls only after publishing its flag) ----
    if (wave == 3) pollw(gflags + 32, (unsigned)(t + 1));  // hr ready
    __syncthreads();                               // Sp2: release
    gather_T(Bh, hrg);                             // Bh := h(t-1).*r
    __syncthreads();                               // S3

    // ---- phase 2 h-part (waves 0,1) + x(t+1) staging (waves 2,3) ----
    if (wave < 2) {
      const short* hb = &Bh[ln * HS + quad * 8];
      #pragma unroll
      for (int kk = 4; kk < KT; ++kk) {
        short8 a = *(const short8*)(hb + (kk - 4) * 32);
        switch (kk & 3) {
          case 0: b0 = __builtin_amdgcn_mfma_f32_16x16x32_bf16(a, bf2[kk], b0, 0, 0, 0); break;
          case 1: b1 = __builtin_amdgcn_mfma_f32_16x16x32_bf16(a, bf2[kk], b1, 0, 0, 0); break;
          case 2: b2 = __builtin_amdgcn_mfma_f32_16x16x32_bf16(a, bf2[kk], b2, 0, 0, 0); break;
          default:b3 = __builtin_amdgcn_mfma_f32_16x16x32_bf16(a, bf2[kk], b3, 0, 0, 0); break;
        }
      }
      floatx4 acc2 = (b0 + b1) + (b2 + b3);
      float hn[4];
      #pragma unroll
      for (int i = 0; i < 4; ++i) {
        int m = quad * 4 + i;
        float hh  = 1.f - 2.f / (__expf(2.f * (acc2[i] + bh)) + 1.f);
        float dec = __expf(-fmaxf(ivals[buf][m] * wint + bint, 0.f));
        float v   = dec * (zf[i] * hold[i] + (1.f - zf[i]) * hh);
        hold[i] = v; hn[i] = v;
      }
      stc8(hg + (size_t)ncol2 * BM + quad * 4,
           pack4(hn[0], hn[1], hn[2], hn[3]));
      asm volatile("s_waitcnt vmcnt(0)" ::: "memory");
      if (lane == 0)
        __hip_atomic_store(&gflags[wg * 2 + wave], (unsigned)(t + 1),
                           __ATOMIC_RELAXED, __HIP_MEMORY_SCOPE_AGENT);
      #pragma unroll
      for (int i = 0; i < 4; ++i) {            // out stores after flag: off critical path
        int m = quad * 4 + i;
        out[((size_t)(g * BM + m) * Tn + t) * Un + ncol2] = hn[i];
      }
    } else if (t + 1 < Tn) {
      int id = tid - 128;               // 0..127
      int row = id >> 3, ch = id & 7;   // 16 shorts per thread
      const float* xr = inp + ((size_t)(g * BM + row) * Tn + (t + 1)) * XFn + ch * 16;
      short8 v0, v1;
      #pragma unroll
      for (int j = 0; j < 8; ++j) { v0[j] = (short)f2bf(xr[j]); v1[j] = (short)f2bf(xr[8 + j]); }
      *(short8*)&Xlds[buf ^ 1][row * XS + ch * 16]     = v0;
      *(short8*)&Xlds[buf ^ 1][row * XS + ch * 16 + 8] = v1;
      if (id < 16)
        ivals[buf ^ 1][id] = inp[((size_t)(g * BM + id) * Tn + (t + 1)) * XFn + Fn];
    }

    __syncthreads();                           // S4: Xlds[buf^1] staged before t+1 x-part
  }
}

extern "C" void kernel_launch(void* const* d_in, const int* in_sizes, int n_in,
                              void* d_out, int out_size, void* d_ws, size_t ws_size,
                              hipStream_t stream) {
  const float* inp  = (const float*)d_in[0];
  const float* h0   = (const float*)d_in[1];
  const float* wz   = (const float*)d_in[2];
  const float* uz   = (const float*)d_in[3];
  const float* bz   = (const float*)d_in[4];
  const float* wr   = (const float*)d_in[5];
  const float* ur   = (const float*)d_in[6];
  const float* br   = (const float*)d_in[7];
  const float* wh   = (const float*)d_in[8];
  const float* uh   = (const float*)d_in[9];
  const float* bh   = (const float*)d_in[10];
  const float* wint = (const float*)d_in[11];
  const float* bint = (const float*)d_in[12];
  float* out = (float*)d_out;

  // ws: [0,4KB) flags | [8KB,264KB) h_buf_T | [264KB,520KB) hr_buf_T
  unsigned* flags       = (unsigned*)d_ws;
  unsigned short* h_buf = (unsigned short*)((char*)d_ws + 8192);
  unsigned short* hr_buf= (unsigned short*)((char*)d_ws + 8192 + (size_t)Bn * Un * 2);

  hipLaunchKernelGGL(init_ws, dim3(4), dim3(256), 0, stream, flags);

  void* args[] = {(void*)&inp, (void*)&h0, (void*)&wz, (void*)&uz, (void*)&bz,
                  (void*)&wr, (void*)&ur, (void*)&br, (void*)&wh, (void*)&uh,
                  (void*)&bh, (void*)&wint, (void*)&bint, (void*)&out,
                  (void*)&h_buf, (void*)&hr_buf, (void*)&flags};
  hipError_t e = hipLaunchCooperativeKernel((void*)gru_kernel, dim3(NG * GC), dim3(256),
                                            args, 0, stream);
  if (e != hipSuccess) {
    hipLaunchKernelGGL(gru_kernel, dim3(NG * GC), dim3(256), 0, stream,
                       inp, h0, wz, uz, bz, wr, ur, br, wh, uh, bh, wint, bint,
                       out, h_buf, hr_buf, flags);
  }
}